// Round 6
// baseline (536.072 us; speedup 1.0000x reference)
//
#include <hip/hip_runtime.h>
#include <stdint.h>

#define BATCH 256
#define M 512
#define N 512
#define K 128

typedef int int4v __attribute__((ext_vector_type(4)));

// R6 = MEASUREMENT ROUND. Kernel body is byte-identical to R0 (best: 361.3us).
// kernel_launch enqueues the kernel THREE times back-to-back (idempotent:
// deterministic output from unchanged inputs, so correctness and absmax are
// unaffected). Purpose: the harness's timed region contains a fixed ~1GB
// poison fill (+ input restore) and the kernel's own dispatch never surfaces
// in the top-5 counter table (<163.5us), so its true duration is unknown in
// [64us(floor), 163us]. dur_us_new - 361.3 = 2 x T_kernel(warm) resolves it;
// a >=164us cold first launch would additionally surface the kernel's own
// FETCH/WRITE/MfmaUtil counter row.
__global__ __launch_bounds__(512, 2) void bmm_s8s8_f32_kernel(
    const int* __restrict__ A32,       // [BATCH, M, K] int32 (values in [-128,127])
    const int* __restrict__ B32,       // [BATCH, N, K] int32
    const float* __restrict__ alpha_p, // scalar
    float* __restrict__ O)             // [BATCH, M, N] fp32
{
    __shared__ int8_t As[M * K]; // 64 KB
    __shared__ int8_t Bs[N * K]; // 64 KB

    const int tid = threadIdx.x;
    const int bat = blockIdx.x;

    const int* Ag = A32 + (size_t)bat * (M * K);
    const int* Bg = B32 + (size_t)bat * (N * K);

    // ---- Stage + pack: 16384 dword-groups per matrix, 512 threads x 32 iters.
    // LDS layout: row-major [row][128] int8 with 16B-chunk XOR swizzle:
    //   byte addr = row*128 + (chunk ^ (row & 7))*16 + sub*4
#pragma unroll 4
    for (int i = 0; i < 32; ++i) {
        const int g   = i * 512 + tid;   // dword-group 0..16383
        const int row = g >> 5;          // 32 groups per 128-int32 row
        const int kg  = g & 31;
        const int kc  = kg >> 2;         // 16B chunk 0..7
        const int sub = kg & 3;
        const int kcs = kc ^ (row & 7);

        int4v wa = *(const int4v*)(Ag + (size_t)g * 4);
        int4v wb = *(const int4v*)(Bg + (size_t)g * 4);
        const int pa = (wa.x & 0xff) | ((wa.y & 0xff) << 8) |
                       ((wa.z & 0xff) << 16) | (wa.w << 24);
        const int pb = (wb.x & 0xff) | ((wb.y & 0xff) << 8) |
                       ((wb.z & 0xff) << 16) | (wb.w << 24);
        *(int*)(As + row * 128 + kcs * 16 + sub * 4) = pa;
        *(int*)(Bs + row * 128 + kcs * 16 + sub * 4) = pb;
    }
    __syncthreads();

    const int lane = tid & 63;
    const int wave = tid >> 6;
    const int l15  = lane & 15;
    const int quad = lane >> 4;
    const int sn   = wave; // supertile column (n-offset sn*64)

    // Hoist B fragments for this wave's column strip.
    int4v bf[2][4];
#pragma unroll
    for (int ks = 0; ks < 2; ++ks)
#pragma unroll
        for (int j = 0; j < 4; ++j) {
            const int rb = sn * 64 + j * 16 + l15;
            const int kc = (ks * 4 + quad) ^ (rb & 7);
            bf[ks][j] = *(const int4v*)(Bs + rb * 128 + kc * 16);
        }

    const float alpha = *alpha_p;

    for (int sm = 0; sm < 8; ++sm) {
        int4v af[2][4];
#pragma unroll
        for (int ks = 0; ks < 2; ++ks)
#pragma unroll
            for (int i = 0; i < 4; ++i) {
                const int ra = sm * 64 + i * 16 + l15;
                const int kc = (ks * 4 + quad) ^ (ra & 7);
                af[ks][i] = *(const int4v*)(As + ra * 128 + kc * 16);
            }

        int4v acc[4][4];
#pragma unroll
        for (int i = 0; i < 4; ++i)
#pragma unroll
            for (int j = 0; j < 4; ++j)
                acc[i][j] = (int4v){0, 0, 0, 0};

#pragma unroll
        for (int ks = 0; ks < 2; ++ks)
#pragma unroll
            for (int i = 0; i < 4; ++i)
#pragma unroll
                for (int j = 0; j < 4; ++j)
                    acc[i][j] = __builtin_amdgcn_mfma_i32_16x16x64_i8(
                        af[ks][i], bf[ks][j], acc[i][j], 0, 0, 0);

        // C/D layout: col = lane&15 (n), row = quad*4 + reg (m).
        float* Ob = O + ((size_t)bat * M + sm * 64 + quad * 4) * N + sn * 64 + l15;
#pragma unroll
        for (int i = 0; i < 4; ++i)
#pragma unroll
            for (int r = 0; r < 4; ++r) {
                float* rowp = Ob + (size_t)(i * 16 + r) * N;
#pragma unroll
                for (int j = 0; j < 4; ++j)
                    rowp[j * 16] = alpha * (float)acc[i][j][r];
            }
    }
}

extern "C" void kernel_launch(void* const* d_in, const int* in_sizes, int n_in,
                              void* d_out, int out_size, void* d_ws, size_t ws_size,
                              hipStream_t stream) {
    const int*   a     = (const int*)d_in[0];
    const int*   b     = (const int*)d_in[1];
    const float* alpha = (const float*)d_in[2];
    float*       out   = (float*)d_out;

    dim3 grid(BATCH);
    dim3 block(512);
    // Triple launch (idempotent): dur_us delta vs single-launch baseline
    // measures 2 x T_kernel(warm) directly.
    bmm_s8s8_f32_kernel<<<grid, block, 0, stream>>>(a, b, alpha, out);
    bmm_s8s8_f32_kernel<<<grid, block, 0, stream>>>(a, b, alpha, out);
    bmm_s8s8_f32_kernel<<<grid, block, 0, stream>>>(a, b, alpha, out);
}

// Round 7
// 399.012 us; speedup vs baseline: 1.3435x; 1.3435x over previous
//
#include <hip/hip_runtime.h>
#include <stdint.h>

#define BATCH 256
#define M 512
#define N 512
#define K 128

typedef int int4v __attribute__((ext_vector_type(4)));

// R7 = PHASE-ISOLATION ROUND. Launch sequence: stage_probe x2, real x1.
// stage_probe = exactly the real kernel's stage phase (global loads + pack +
// swizzled ds_write + syncthreads) with an asm-sink keep-alive and NO global
// writes. The final real launch produces the correct output, so correctness
// is unaffected. dur_us - 361.3 = 2 x T_stage localizes which phase of the
// 87us kernel (R6 measurement) is running below bandwidth:
//   stage ideal ~21us (HBM) / ~11us (L3-warm); store ideal ~41us; sum+compute
//   ~65us vs 87us measured -> ~22us lives in ONE of the phases.
__global__ __launch_bounds__(512, 2) void stage_probe(
    const int* __restrict__ A32,
    const int* __restrict__ B32,
    const float* __restrict__ alpha_p,
    float* __restrict__ O)
{
    __shared__ int8_t As[M * K]; // 64 KB
    __shared__ int8_t Bs[N * K]; // 64 KB

    const int tid = threadIdx.x;
    const int bat = blockIdx.x;

    const int* Ag = A32 + (size_t)bat * (M * K);
    const int* Bg = B32 + (size_t)bat * (N * K);

#pragma unroll 4
    for (int i = 0; i < 32; ++i) {
        const int g   = i * 512 + tid;
        const int row = g >> 5;
        const int kg  = g & 31;
        const int kc  = kg >> 2;
        const int sub = kg & 3;
        const int kcs = kc ^ (row & 7);

        int4v wa = *(const int4v*)(Ag + (size_t)g * 4);
        int4v wb = *(const int4v*)(Bg + (size_t)g * 4);
        const int pa = (wa.x & 0xff) | ((wa.y & 0xff) << 8) |
                       ((wa.z & 0xff) << 16) | (wa.w << 24);
        const int pb = (wb.x & 0xff) | ((wb.y & 0xff) << 8) |
                       ((wb.z & 0xff) << 16) | (wb.w << 24);
        *(int*)(As + row * 128 + kcs * 16 + sub * 4) = pa;
        *(int*)(Bs + row * 128 + kcs * 16 + sub * 4) = pb;
    }
    __syncthreads();

    // Keep-alive: data-dependent LDS reads sunk into an asm token (rule #17);
    // opaque enough that no ds_write can be proven dead. No global stores.
    int sa = *(int*)(As + ((tid * 67) & 65532));
    int sb = *(int*)(Bs + ((tid * 131) & 65532));
    asm volatile("" :: "v"(sa), "v"(sb));
}

// Real kernel: byte-identical to R0 (best: 361.3us single-launch).
__global__ __launch_bounds__(512, 2) void bmm_s8s8_f32_kernel(
    const int* __restrict__ A32,       // [BATCH, M, K] int32 (values in [-128,127])
    const int* __restrict__ B32,       // [BATCH, N, K] int32
    const float* __restrict__ alpha_p, // scalar
    float* __restrict__ O)             // [BATCH, M, N] fp32
{
    __shared__ int8_t As[M * K]; // 64 KB
    __shared__ int8_t Bs[N * K]; // 64 KB

    const int tid = threadIdx.x;
    const int bat = blockIdx.x;

    const int* Ag = A32 + (size_t)bat * (M * K);
    const int* Bg = B32 + (size_t)bat * (N * K);

#pragma unroll 4
    for (int i = 0; i < 32; ++i) {
        const int g   = i * 512 + tid;   // dword-group 0..16383
        const int row = g >> 5;          // 32 groups per 128-int32 row
        const int kg  = g & 31;
        const int kc  = kg >> 2;         // 16B chunk 0..7
        const int sub = kg & 3;
        const int kcs = kc ^ (row & 7);

        int4v wa = *(const int4v*)(Ag + (size_t)g * 4);
        int4v wb = *(const int4v*)(Bg + (size_t)g * 4);
        const int pa = (wa.x & 0xff) | ((wa.y & 0xff) << 8) |
                       ((wa.z & 0xff) << 16) | (wa.w << 24);
        const int pb = (wb.x & 0xff) | ((wb.y & 0xff) << 8) |
                       ((wb.z & 0xff) << 16) | (wb.w << 24);
        *(int*)(As + row * 128 + kcs * 16 + sub * 4) = pa;
        *(int*)(Bs + row * 128 + kcs * 16 + sub * 4) = pb;
    }
    __syncthreads();

    const int lane = tid & 63;
    const int wave = tid >> 6;
    const int l15  = lane & 15;
    const int quad = lane >> 4;
    const int sn   = wave; // supertile column (n-offset sn*64)

    int4v bf[2][4];
#pragma unroll
    for (int ks = 0; ks < 2; ++ks)
#pragma unroll
        for (int j = 0; j < 4; ++j) {
            const int rb = sn * 64 + j * 16 + l15;
            const int kc = (ks * 4 + quad) ^ (rb & 7);
            bf[ks][j] = *(const int4v*)(Bs + rb * 128 + kc * 16);
        }

    const float alpha = *alpha_p;

    for (int sm = 0; sm < 8; ++sm) {
        int4v af[2][4];
#pragma unroll
        for (int ks = 0; ks < 2; ++ks)
#pragma unroll
            for (int i = 0; i < 4; ++i) {
                const int ra = sm * 64 + i * 16 + l15;
                const int kc = (ks * 4 + quad) ^ (ra & 7);
                af[ks][i] = *(const int4v*)(As + ra * 128 + kc * 16);
            }

        int4v acc[4][4];
#pragma unroll
        for (int i = 0; i < 4; ++i)
#pragma unroll
            for (int j = 0; j < 4; ++j)
                acc[i][j] = (int4v){0, 0, 0, 0};

#pragma unroll
        for (int ks = 0; ks < 2; ++ks)
#pragma unroll
            for (int i = 0; i < 4; ++i)
#pragma unroll
                for (int j = 0; j < 4; ++j)
                    acc[i][j] = __builtin_amdgcn_mfma_i32_16x16x64_i8(
                        af[ks][i], bf[ks][j], acc[i][j], 0, 0, 0);

        // C/D layout: col = lane&15 (n), row = quad*4 + reg (m).
        float* Ob = O + ((size_t)bat * M + sm * 64 + quad * 4) * N + sn * 64 + l15;
#pragma unroll
        for (int i = 0; i < 4; ++i)
#pragma unroll
            for (int r = 0; r < 4; ++r) {
                float* rowp = Ob + (size_t)(i * 16 + r) * N;
#pragma unroll
                for (int j = 0; j < 4; ++j)
                    rowp[j * 16] = alpha * (float)acc[i][j][r];
            }
    }
}

extern "C" void kernel_launch(void* const* d_in, const int* in_sizes, int n_in,
                              void* d_out, int out_size, void* d_ws, size_t ws_size,
                              hipStream_t stream) {
    const int*   a     = (const int*)d_in[0];
    const int*   b     = (const int*)d_in[1];
    const float* alpha = (const float*)d_in[2];
    float*       out   = (float*)d_out;

    dim3 grid(BATCH);
    dim3 block(512);
    // Probe x2 (no output writes), then the real kernel (correct output).
    stage_probe<<<grid, block, 0, stream>>>(a, b, alpha, out);
    stage_probe<<<grid, block, 0, stream>>>(a, b, alpha, out);
    bmm_s8s8_f32_kernel<<<grid, block, 0, stream>>>(a, b, alpha, out);
}